// Round 17
// baseline (3469.738 us; speedup 1.0000x reference)
//
#include <hip/hip_runtime.h>

#define TSTEPS 8192
#define H 51
#define SE 8                     // timesteps per barrier epoch
#define NEPOCH (TSTEPS / SE + 3) // 4 pipeline stages -> +3 epochs

typedef float  f4 __attribute__((ext_vector_type(4)));
typedef int    i4 __attribute__((ext_vector_type(4)));
typedef int    i2 __attribute__((ext_vector_type(2)));
typedef _Float16 h2 __attribute__((ext_vector_type(2)));

#define LOG2E 1.44269504f

__device__ __forceinline__ int rl_i(int v, int k) { return __builtin_amdgcn_readlane(v, k); }
__device__ __forceinline__ h2 asp(int v) { union { int i; h2 h; } u; u.i = v; return u.h; }
__device__ __forceinline__ int ash(h2 v) { union { int i; h2 h; } u; u.h = v; return u.i; }

__device__ __forceinline__ float fdot2(h2 a, h2 b, float c) {
#if __has_builtin(__builtin_amdgcn_fdot2)
    return __builtin_amdgcn_fdot2(a, b, c, false);
#else
    return fmaf((float)a[0], (float)b[0], fmaf((float)a[1], (float)b[1], c));
#endif
}
// inputs pre-scaled by log2e: sigmoid via raw v_exp_f32 (no mul on the chain)
__device__ __forceinline__ float sig2(float x) {
    return __builtin_amdgcn_rcpf(1.0f + exp2f(-x));
}
// inputs pre-scaled by 2*log2e: gate tanh, |x| <= ~22 -> finite, no clamp
__device__ __forceinline__ float tanh2(float x) {
    const float t = exp2f(-x);
    return (1.0f - t) * __builtin_amdgcn_rcpf(1.0f + t);
}
// tanh of UNSCALED cell state (clamped: c can grow over time)
__device__ __forceinline__ float tanh_c(float x) {
    x = fminf(fmaxf(x, -15.0f), 15.0f);
    const float t = exp2f(-2.88539008f * x);
    return (1.0f - t) * __builtin_amdgcn_rcpf(1.0f + t);
}
// f16-RNE pack of one k-pair of a weight row, pre-scaled by s
__device__ __forceinline__ int packpair(const float* Wrow, int j, float s) {
    const float w0 = (2 * j < H) ? s * Wrow[2 * j] : 0.0f;
    const float w1 = (2 * j + 1 < H) ? s * Wrow[2 * j + 1] : 0.0f;
    h2 p; p[0] = (_Float16)w0; p[1] = (_Float16)w1; return ash(p);
}
// lane j <- {h(lane 2j), h(lane 2j+1)} packed to f16x2 (RNE), in-register
__device__ __forceinline__ int packpairs_bperm(float hval, int a0, int a1) {
    const int hi = __float_as_int(hval);
    const float v0 = __int_as_float(__builtin_amdgcn_ds_bpermute(a0, hi));
    const float v1 = __int_as_float(__builtin_amdgcn_ds_bpermute(a1, hi));
    h2 pk; pk[0] = (_Float16)v0; pk[1] = (_Float16)v1;
    return ash(pk);
}

// R17 (final) = R13 EXACTLY (best measured: 3231 us — in-dot readlanes,
// interleaved 8-accumulator DOT26, SE=8, f16-pair weights at 104 VGPR/wave
// under the 132-VGPR wall, PIN-once, bpermute h-pack, 4-wave pipeline)
// + the single proven-safe delta from R15/R16: log2e / 2*log2e folded into
// the f16 weights and biases, deleting one v_mul from every activation's
// serial tail (adds no registers, moves no instructions; absmax unchanged
// at 2.44e-4 in both rounds that carried it). R16's hb[26] hoist is
// REVERTED (26 extra live regs + a serialization point: +200 us).
//   wave0 @e: steps 8e..8e+7 : h1 = cell1(Whh1.h1 + x)   [in-wave serial]
//   wave2 @e: steps 8(e-1)+j : z2a = Wih2.h1             [8 indep dots]
//   wave1 @e: steps 8(e-2)+j : u2 dot (in-wave) + cell2  [in-wave serial]
//   wave3 @e: steps 8(e-3)+j : out = Wlin.h2 + blin      [off-path]
#define DECLG(g) i4 wq##g##_0, wq##g##_1, wq##g##_2, wq##g##_3, wq##g##_4, wq##g##_5; i2 wq##g##_6;
#define LOADG(g, RP, S) { const float* _r = (RP); const float _s = (S); \
    i4 t0 = {packpair(_r,0,_s),  packpair(_r,1,_s),  packpair(_r,2,_s),  packpair(_r,3,_s)};  wq##g##_0 = t0; \
    i4 t1 = {packpair(_r,4,_s),  packpair(_r,5,_s),  packpair(_r,6,_s),  packpair(_r,7,_s)};  wq##g##_1 = t1; \
    i4 t2 = {packpair(_r,8,_s),  packpair(_r,9,_s),  packpair(_r,10,_s), packpair(_r,11,_s)}; wq##g##_2 = t2; \
    i4 t3 = {packpair(_r,12,_s), packpair(_r,13,_s), packpair(_r,14,_s), packpair(_r,15,_s)}; wq##g##_3 = t3; \
    i4 t4 = {packpair(_r,16,_s), packpair(_r,17,_s), packpair(_r,18,_s), packpair(_r,19,_s)}; wq##g##_4 = t4; \
    i4 t5 = {packpair(_r,20,_s), packpair(_r,21,_s), packpair(_r,22,_s), packpair(_r,23,_s)}; wq##g##_5 = t5; \
    i2 t6 = {packpair(_r,24,_s), packpair(_r,25,_s)};                                         wq##g##_6 = t6; }
#define PING(g) asm("" : "+v"(wq##g##_0), "+v"(wq##g##_1), "+v"(wq##g##_2), \
                        "+v"(wq##g##_3), "+v"(wq##g##_4), "+v"(wq##g##_5), "+v"(wq##g##_6));
// R13's structure: readlane inline in the dot, two interleaved accumulator sets
#define DJA(j,q,e) { const int _hb = rl_i(_hs, j); \
    a0 = fdot2(asp(wq0_##q[e]), asp(_hb), a0); \
    a1 = fdot2(asp(wq1_##q[e]), asp(_hb), a1); \
    a2 = fdot2(asp(wq2_##q[e]), asp(_hb), a2); \
    a3 = fdot2(asp(wq3_##q[e]), asp(_hb), a3); }
#define DJB(j,q,e) { const int _hb = rl_i(_hs, j); \
    b0 = fdot2(asp(wq0_##q[e]), asp(_hb), b0); \
    b1 = fdot2(asp(wq1_##q[e]), asp(_hb), b1); \
    b2 = fdot2(asp(wq2_##q[e]), asp(_hb), b2); \
    b3 = fdot2(asp(wq3_##q[e]), asp(_hb), b3); }
#define DOT26 \
    DJA(0,0,0) DJB(1,0,1) DJA(2,0,2) DJB(3,0,3) DJA(4,1,0) DJB(5,1,1) DJA(6,1,2) DJB(7,1,3) \
    DJA(8,2,0) DJB(9,2,1) DJA(10,2,2) DJB(11,2,3) DJA(12,3,0) DJB(13,3,1) DJA(14,3,2) DJB(15,3,3) \
    DJA(16,4,0) DJB(17,4,1) DJA(18,4,2) DJB(19,4,3) DJA(20,5,0) DJB(21,5,1) DJA(22,5,2) DJB(23,5,3) \
    DJA(24,6,0) DJB(25,6,1)

__global__ __launch_bounds__(256) __attribute__((amdgpu_waves_per_eu(1, 1)))
void lstm2_final_kernel(const float* __restrict__ x,
                        const float* __restrict__ Wih1,
                        const float* __restrict__ Whh1,
                        const float* __restrict__ bih1,
                        const float* __restrict__ bhh1,
                        const float* __restrict__ Wih2,
                        const float* __restrict__ Whh2,
                        const float* __restrict__ bih2,
                        const float* __restrict__ bhh2,
                        const float* __restrict__ Wlin,
                        const float* __restrict__ blin,
                        float* __restrict__ out)
{
    __shared__ __align__(16) float sh_x[TSTEPS];
    __shared__ __align__(16) float sh_out[TSTEPS];
    __shared__ __align__(16) int   sh_hpk1[2][SE][64];  // packed h1 (wave0 -> wave2)
    __shared__ __align__(16) f4    sh_z2a[2][SE][64];   // scaled Wih2.h1 (wave2 -> wave1)
    __shared__ __align__(16) float sh_h2f[2][SE][64];   // f32 h2 (wave1 -> wave3)

    const int tid  = threadIdx.x;
    const int wave = tid >> 6;
    const int lane = tid & 63;
    const int row  = (lane < H) ? lane : (H - 1);
    const int pa0  = (2 * lane) * 4;
    const int pa1  = (2 * lane + 1) * 4;

    for (int i = tid; i < TSTEPS / 4; i += 256)
        ((f4*)sh_x)[i] = ((const f4*)x)[i];

    // per-gate activation scale folded into weights: sigmoid log2e, tanh 2*log2e
    const float scl[4] = {LOG2E, LOG2E, 2.0f * LOG2E, LOG2E};

    const float* Mp = (wave == 0) ? Whh1 : (wave == 1) ? Whh2 : Wih2;
    DECLG(0) DECLG(1) DECLG(2) DECLG(3)
    LOADG(0, Mp + (0 * H + row) * H, scl[0])
    LOADG(1, Mp + (1 * H + row) * H, scl[1])
    LOADG(2, Mp + (2 * H + row) * H, scl[2])
    LOADG(3, Mp + (3 * H + row) * H, scl[3])
    PING(0) PING(1) PING(2) PING(3)

    f4 b1v, wx4, b2v;
#pragma unroll
    for (int g = 0; g < 4; ++g) {
        b1v[g] = scl[g] * (bih1[g * H + row] + bhh1[g * H + row]);
        wx4[g] = scl[g] * Wih1[g * H + row];
        b2v[g] = scl[g] * (bih2[g * H + row] + bhh2[g * H + row]);
    }
    const float wlin = (lane < H) ? Wlin[lane] : 0.0f;
    const float bl   = blin[0];

    if (tid < 64) {
#pragma unroll
        for (int b = 0; b < 2; ++b)
#pragma unroll
            for (int j = 0; j < SE; ++j) {
                sh_hpk1[b][j][tid] = 0;
                sh_z2a[b][j][tid] = (f4)0.0f;
                sh_h2f[b][j][tid] = 0.0f;
            }
    }
    float c1 = 0.0f, c2 = 0.0f;
    int hpk1reg = 0, hpk2reg = 0;
    __syncthreads();

#pragma unroll 1
    for (int e = 0; e < NEPOCH; ++e) {
        if (wave == 0) {
            // ---- steps 8e..8e+7: layer-1 self-loop, fully in-wave ----
            if (e < TSTEPS / SE) {
                const f4 xs0 = ((const f4*)sh_x)[2 * e];
                const f4 xs1 = ((const f4*)sh_x)[2 * e + 1];
#pragma unroll
                for (int j = 0; j < SE; ++j) {
                    const float xv = (j < 4) ? xs0[j & 3] : xs1[j & 3];
                    float a0 = fmaf(wx4[0], xv, b1v[0]);
                    float a1 = fmaf(wx4[1], xv, b1v[1]);
                    float a2 = fmaf(wx4[2], xv, b1v[2]);
                    float a3 = fmaf(wx4[3], xv, b1v[3]);
                    float b0 = 0.0f, b1 = 0.0f, b2 = 0.0f, b3 = 0.0f;
                    const int _hs = hpk1reg;
                    DOT26
                    const float si = sig2(a0 + b0), sf = sig2(a1 + b1);
                    const float tg = tanh2(a2 + b2), so = sig2(a3 + b3);
                    c1 = fmaf(sf, c1, si * tg);
                    const float h1n = (lane < H) ? so * tanh_c(c1) : 0.0f;
                    hpk1reg = packpairs_bperm(h1n, pa0, pa1);
                    sh_hpk1[e & 1][j][lane] = hpk1reg;
                }
            }
        } else if (wave == 2) {
            // ---- steps 8(e-1)+j: z2a = (scaled Wih2).h1 — 8 indep dots ----
            if (e >= 1 && e <= TSTEPS / SE) {
                int hp[SE];
#pragma unroll
                for (int j = 0; j < SE; ++j) hp[j] = sh_hpk1[(e - 1) & 1][j][lane];
#pragma unroll
                for (int j = 0; j < SE; ++j) {
                    const int _hs = hp[j];
                    float a0 = 0.0f, a1 = 0.0f, a2 = 0.0f, a3 = 0.0f;
                    float b0 = 0.0f, b1 = 0.0f, b2 = 0.0f, b3 = 0.0f;
                    DOT26
                    f4 z; z[0] = a0 + b0; z[1] = a1 + b1; z[2] = a2 + b2; z[3] = a3 + b3;
                    sh_z2a[e & 1][j][lane] = z;
                }
            }
        } else if (wave == 1) {
            // ---- steps 8(e-2)+j: u2 dot (in-wave h2 self-loop) + cell2 ----
            if (e >= 2 && e <= TSTEPS / SE + 1) {
                f4 za[SE];
#pragma unroll
                for (int j = 0; j < SE; ++j) za[j] = sh_z2a[(e - 1) & 1][j][lane];
#pragma unroll
                for (int j = 0; j < SE; ++j) {
                    float a0 = b2v[0], a1 = b2v[1], a2 = b2v[2], a3 = b2v[3];
                    float b0 = 0.0f, b1 = 0.0f, b2 = 0.0f, b3 = 0.0f;
                    const int _hs = hpk2reg;
                    DOT26
                    const float si = sig2(za[j][0] + a0 + b0);
                    const float sf = sig2(za[j][1] + a1 + b1);
                    const float tg = tanh2(za[j][2] + a2 + b2);
                    const float so = sig2(za[j][3] + a3 + b3);
                    c2 = fmaf(sf, c2, si * tg);
                    const float h2n = (lane < H) ? so * tanh_c(c2) : 0.0f;
                    sh_h2f[e & 1][j][lane] = h2n;
                    hpk2reg = packpairs_bperm(h2n, pa0, pa1);
                }
            }
        } else {
            // ---- steps 8(e-3)+j: out = Wlin.h2 + blin (off critical path) ----
            if (e >= 3) {
                const int base = (e - 3) * SE;
                float p[SE];
#pragma unroll
                for (int j = 0; j < SE; ++j)
                    p[j] = sh_h2f[(e - 1) & 1][j][lane] * wlin;
#pragma unroll
                for (int off = 32; off >= 1; off >>= 1) {
#pragma unroll
                    for (int j = 0; j < SE; ++j) p[j] += __shfl_down(p[j], off);
                }
                if (lane == 0) {
#pragma unroll
                    for (int j = 0; j < SE; ++j) sh_out[base + j] = p[j] + bl;
                }
            }
        }
        __syncthreads();
    }

    for (int i = tid; i < TSTEPS / 4; i += 256)
        ((f4*)out)[i] = ((const f4*)sh_out)[i];
}

extern "C" void kernel_launch(void* const* d_in, const int* in_sizes, int n_in,
                              void* d_out, int out_size, void* d_ws, size_t ws_size,
                              hipStream_t stream) {
    const float* x    = (const float*)d_in[0];
    const float* Wih1 = (const float*)d_in[1];
    const float* Whh1 = (const float*)d_in[2];
    const float* bih1 = (const float*)d_in[3];
    const float* bhh1 = (const float*)d_in[4];
    const float* Wih2 = (const float*)d_in[5];
    const float* Whh2 = (const float*)d_in[6];
    const float* bih2 = (const float*)d_in[7];
    const float* bhh2 = (const float*)d_in[8];
    const float* Wlin = (const float*)d_in[9];
    const float* blin = (const float*)d_in[10];
    float* out = (float*)d_out;

    lstm2_final_kernel<<<1, 256, 0, stream>>>(
        x, Wih1, Whh1, bih1, bhh1, Wih2, Whh2, bih2, bhh2, Wlin, blin, out);
}

// Round 18
// 3213.994 us; speedup vs baseline: 1.0796x; 1.0796x over previous
//
#include <hip/hip_runtime.h>

#define TSTEPS 8192
#define H 51
#define SE 8                     // timesteps per barrier epoch
#define NEPOCH (TSTEPS / SE + 3) // 4 pipeline stages -> +3 epochs

typedef float  f2 __attribute__((ext_vector_type(2)));
typedef float  f4 __attribute__((ext_vector_type(4)));
typedef int    i4 __attribute__((ext_vector_type(4)));
typedef int    i2 __attribute__((ext_vector_type(2)));
typedef _Float16 h2 __attribute__((ext_vector_type(2)));

__device__ __forceinline__ int rl_i(int v, int k) { return __builtin_amdgcn_readlane(v, k); }
__device__ __forceinline__ h2 asp(int v) { union { int i; h2 h; } u; u.i = v; return u.h; }
__device__ __forceinline__ int ash(h2 v) { union { int i; h2 h; } u; u.h = v; return u.i; }

__device__ __forceinline__ float fdot2(h2 a, h2 b, float c) {
#if __has_builtin(__builtin_amdgcn_fdot2)
    return __builtin_amdgcn_fdot2(a, b, c, false);
#else
    return fmaf((float)a[0], (float)b[0], fmaf((float)a[1], (float)b[1], c));
#endif
}
__device__ __forceinline__ float sigmoidf_fast(float x) {
    return __builtin_amdgcn_rcpf(1.0f + __expf(-x));
}
__device__ __forceinline__ float tanhf_fast(float x) {
    x = fminf(fmaxf(x, -15.0f), 15.0f);
    float t = __expf(-2.0f * x);
    return (1.0f - t) * __builtin_amdgcn_rcpf(1.0f + t);
}
__device__ __forceinline__ int packpair(const float* Wrow, int j) {
    const float w0 = (2 * j < H) ? Wrow[2 * j] : 0.0f;
    const float w1 = (2 * j + 1 < H) ? Wrow[2 * j + 1] : 0.0f;
    h2 p; p[0] = (_Float16)w0; p[1] = (_Float16)w1; return ash(p);
}
// lane j <- {h(lane 2j), h(lane 2j+1)} packed to f16x2 (RNE), in-register
__device__ __forceinline__ int packpairs_bperm(float hval, int a0, int a1) {
    const int hi = __float_as_int(hval);
    const float v0 = __int_as_float(__builtin_amdgcn_ds_bpermute(a0, hi));
    const float v1 = __int_as_float(__builtin_amdgcn_ds_bpermute(a1, hi));
    h2 pk; pk[0] = (_Float16)v0; pk[1] = (_Float16)v1;
    return ash(pk);
}

// R18 = R13 restored verbatim — the measured optimum of this structure
// (3231 us). R14 (asm dot2), R15 (gate-sequenced dots + log2e fold),
// R16 (hoisted readlanes + fold), R17 (fold only) each regressed by
// 150-250 us: four independent perturbations around R13 all lose, so R13
// is a local optimum and the session's final configuration.
//   wave0 @e: steps 8e..8e+7   : h1 = cell1(Whh1.h1 + x)   [in-wave serial]
//   wave2 @e: steps 8(e-1)+j   : z2a = Wih2.h1             [8 indep dots]
//   wave1 @e: steps 8(e-2)+j   : u2 dot (in-wave) + cell2  [in-wave serial]
//   wave3 @e: steps 8(e-3)+j   : out = Wlin.h2 + blin      [off-path]
// Key invariants learned: (1) >~130 live floats/thread always spills
// (R2/R6/R9); f16-pair weights at 104 VGPR/wave fit. (2) asm "+v" PIN once
// prevents remat/sink (R7's silent reload bug). (3) per-CU DS pipe
// saturates at ~200 DS-ops/epoch (R8); readlane broadcasts are free.
// (4) barrier+drain costs ~650 cyc/epoch -> amortize with SE steps/epoch.
#define DECLG(g) i4 wq##g##_0, wq##g##_1, wq##g##_2, wq##g##_3, wq##g##_4, wq##g##_5; i2 wq##g##_6;
#define LOADG(g, RP) { const float* _r = (RP); \
    i4 t0 = {packpair(_r,0),  packpair(_r,1),  packpair(_r,2),  packpair(_r,3)};  wq##g##_0 = t0; \
    i4 t1 = {packpair(_r,4),  packpair(_r,5),  packpair(_r,6),  packpair(_r,7)};  wq##g##_1 = t1; \
    i4 t2 = {packpair(_r,8),  packpair(_r,9),  packpair(_r,10), packpair(_r,11)}; wq##g##_2 = t2; \
    i4 t3 = {packpair(_r,12), packpair(_r,13), packpair(_r,14), packpair(_r,15)}; wq##g##_3 = t3; \
    i4 t4 = {packpair(_r,16), packpair(_r,17), packpair(_r,18), packpair(_r,19)}; wq##g##_4 = t4; \
    i4 t5 = {packpair(_r,20), packpair(_r,21), packpair(_r,22), packpair(_r,23)}; wq##g##_5 = t5; \
    i2 t6 = {packpair(_r,24), packpair(_r,25)};                                   wq##g##_6 = t6; }
#define PING(g) asm("" : "+v"(wq##g##_0), "+v"(wq##g##_1), "+v"(wq##g##_2), \
                        "+v"(wq##g##_3), "+v"(wq##g##_4), "+v"(wq##g##_5), "+v"(wq##g##_6));
// two interleaved accumulator sets: a* (even j) and b* (odd j) -> depth 13
#define DJA(j,q,e) { const h2 _hb = asp(rl_i(_hs, j)); \
    a0 = fdot2(asp(wq0_##q[e]), _hb, a0); \
    a1 = fdot2(asp(wq1_##q[e]), _hb, a1); \
    a2 = fdot2(asp(wq2_##q[e]), _hb, a2); \
    a3 = fdot2(asp(wq3_##q[e]), _hb, a3); }
#define DJB(j,q,e) { const h2 _hb = asp(rl_i(_hs, j)); \
    b0 = fdot2(asp(wq0_##q[e]), _hb, b0); \
    b1 = fdot2(asp(wq1_##q[e]), _hb, b1); \
    b2 = fdot2(asp(wq2_##q[e]), _hb, b2); \
    b3 = fdot2(asp(wq3_##q[e]), _hb, b3); }
#define DOT26 \
    DJA(0,0,0) DJB(1,0,1) DJA(2,0,2) DJB(3,0,3) DJA(4,1,0) DJB(5,1,1) DJA(6,1,2) DJB(7,1,3) \
    DJA(8,2,0) DJB(9,2,1) DJA(10,2,2) DJB(11,2,3) DJA(12,3,0) DJB(13,3,1) DJA(14,3,2) DJB(15,3,3) \
    DJA(16,4,0) DJB(17,4,1) DJA(18,4,2) DJB(19,4,3) DJA(20,5,0) DJB(21,5,1) DJA(22,5,2) DJB(23,5,3) \
    DJA(24,6,0) DJB(25,6,1)

__global__ __launch_bounds__(256) __attribute__((amdgpu_waves_per_eu(1, 1)))
void lstm2_b8_kernel(const float* __restrict__ x,
                     const float* __restrict__ Wih1,
                     const float* __restrict__ Whh1,
                     const float* __restrict__ bih1,
                     const float* __restrict__ bhh1,
                     const float* __restrict__ Wih2,
                     const float* __restrict__ Whh2,
                     const float* __restrict__ bih2,
                     const float* __restrict__ bhh2,
                     const float* __restrict__ Wlin,
                     const float* __restrict__ blin,
                     float* __restrict__ out)
{
    __shared__ __align__(16) float sh_x[TSTEPS];
    __shared__ __align__(16) float sh_out[TSTEPS];
    __shared__ __align__(16) int   sh_hpk1[2][SE][64];  // packed h1 (wave0 -> wave2)
    __shared__ __align__(16) f4    sh_z2a[2][SE][64];   // raw Wih2.h1 (wave2 -> wave1)
    __shared__ __align__(16) float sh_h2f[2][SE][64];   // f32 h2 (wave1 -> wave3)

    const int tid  = threadIdx.x;
    const int wave = tid >> 6;
    const int lane = tid & 63;
    const int row  = (lane < H) ? lane : (H - 1);
    const int pa0  = (2 * lane) * 4;
    const int pa1  = (2 * lane + 1) * 4;

    for (int i = tid; i < TSTEPS / 4; i += 256)
        ((f4*)sh_x)[i] = ((const f4*)x)[i];

    // ---- per-wave matrix as 104 packed f16-pair registers, pinned once ----
    const float* Mp = (wave == 0) ? Whh1 : (wave == 1) ? Whh2 : Wih2;
    DECLG(0) DECLG(1) DECLG(2) DECLG(3)
    LOADG(0, Mp + (0 * H + row) * H)
    LOADG(1, Mp + (1 * H + row) * H)
    LOADG(2, Mp + (2 * H + row) * H)
    LOADG(3, Mp + (3 * H + row) * H)
    PING(0) PING(1) PING(2) PING(3)

    f4 b1v, wx4, b2v;
#pragma unroll
    for (int g = 0; g < 4; ++g) {
        b1v[g] = bih1[g * H + row] + bhh1[g * H + row];
        wx4[g] = Wih1[g * H + row];
        b2v[g] = bih2[g * H + row] + bhh2[g * H + row];
    }
    const float wlin = (lane < H) ? Wlin[lane] : 0.0f;
    const float bl   = blin[0];

    if (tid < 64) {
#pragma unroll
        for (int b = 0; b < 2; ++b)
#pragma unroll
            for (int j = 0; j < SE; ++j) {
                sh_hpk1[b][j][tid] = 0;
                sh_z2a[b][j][tid] = (f4)0.0f;
                sh_h2f[b][j][tid] = 0.0f;
            }
    }
    float c1 = 0.0f, c2 = 0.0f;
    int hpk1reg = 0, hpk2reg = 0;
    __syncthreads();

#pragma unroll 1
    for (int e = 0; e < NEPOCH; ++e) {
        if (wave == 0) {
            // ---- steps 8e..8e+7: layer-1 self-loop, fully in-wave ----
            if (e < TSTEPS / SE) {
                const f4 xs0 = ((const f4*)sh_x)[2 * e];
                const f4 xs1 = ((const f4*)sh_x)[2 * e + 1];
#pragma unroll
                for (int j = 0; j < SE; ++j) {
                    const float xv = (j < 4) ? xs0[j & 3] : xs1[j & 3];
                    // x-FMA folded into acc init (off the post-dot tail)
                    float a0 = fmaf(wx4[0], xv, b1v[0]);
                    float a1 = fmaf(wx4[1], xv, b1v[1]);
                    float a2 = fmaf(wx4[2], xv, b1v[2]);
                    float a3 = fmaf(wx4[3], xv, b1v[3]);
                    float b0 = 0.0f, b1 = 0.0f, b2 = 0.0f, b3 = 0.0f;
                    const int _hs = hpk1reg;
                    DOT26
                    const float ig = sigmoidf_fast(a0 + b0), fg = sigmoidf_fast(a1 + b1);
                    const float gg = tanhf_fast(a2 + b2),    og = sigmoidf_fast(a3 + b3);
                    c1 = fmaf(fg, c1, ig * gg);
                    const float h1n = (lane < H) ? og * tanhf_fast(c1) : 0.0f;
                    hpk1reg = packpairs_bperm(h1n, pa0, pa1);
                    sh_hpk1[e & 1][j][lane] = hpk1reg;
                }
            }
        } else if (wave == 2) {
            // ---- steps 8(e-1)+j: z2a = Wih2.h1 (8 independent dots) ----
            if (e >= 1 && e <= TSTEPS / SE) {
                int hp[SE];
#pragma unroll
                for (int j = 0; j < SE; ++j) hp[j] = sh_hpk1[(e - 1) & 1][j][lane];
#pragma unroll
                for (int j = 0; j < SE; ++j) {
                    const int _hs = hp[j];
                    float a0 = 0.0f, a1 = 0.0f, a2 = 0.0f, a3 = 0.0f;
                    float b0 = 0.0f, b1 = 0.0f, b2 = 0.0f, b3 = 0.0f;
                    DOT26
                    f4 z; z[0] = a0 + b0; z[1] = a1 + b1; z[2] = a2 + b2; z[3] = a3 + b3;
                    sh_z2a[e & 1][j][lane] = z;
                }
            }
        } else if (wave == 1) {
            // ---- steps 8(e-2)+j: u2 dot (in-wave h2 self-loop) + cell2 ----
            if (e >= 2 && e <= TSTEPS / SE + 1) {
                f4 za[SE];
#pragma unroll
                for (int j = 0; j < SE; ++j) za[j] = sh_z2a[(e - 1) & 1][j][lane];
#pragma unroll
                for (int j = 0; j < SE; ++j) {
                    float a0 = b2v[0], a1 = b2v[1], a2 = b2v[2], a3 = b2v[3];
                    float b0 = 0.0f, b1 = 0.0f, b2 = 0.0f, b3 = 0.0f;
                    const int _hs = hpk2reg;
                    DOT26
                    const float ig = sigmoidf_fast(za[j][0] + a0 + b0);
                    const float fg = sigmoidf_fast(za[j][1] + a1 + b1);
                    const float gg = tanhf_fast   (za[j][2] + a2 + b2);
                    const float og = sigmoidf_fast(za[j][3] + a3 + b3);
                    c2 = fmaf(fg, c2, ig * gg);
                    const float h2n = (lane < H) ? og * tanhf_fast(c2) : 0.0f;
                    sh_h2f[e & 1][j][lane] = h2n;
                    hpk2reg = packpairs_bperm(h2n, pa0, pa1);
                }
            }
        } else {
            // ---- steps 8(e-3)+j: out = Wlin.h2 + blin (off critical path) ----
            if (e >= 3) {
                const int base = (e - 3) * SE;
                float p[SE];
#pragma unroll
                for (int j = 0; j < SE; ++j)
                    p[j] = sh_h2f[(e - 1) & 1][j][lane] * wlin;
#pragma unroll
                for (int off = 32; off >= 1; off >>= 1) {
#pragma unroll
                    for (int j = 0; j < SE; ++j) p[j] += __shfl_down(p[j], off);
                }
                if (lane == 0) {
#pragma unroll
                    for (int j = 0; j < SE; ++j) sh_out[base + j] = p[j] + bl;
                }
            }
        }
        __syncthreads();
    }

    for (int i = tid; i < TSTEPS / 4; i += 256)
        ((f4*)out)[i] = ((const f4*)sh_out)[i];
}

extern "C" void kernel_launch(void* const* d_in, const int* in_sizes, int n_in,
                              void* d_out, int out_size, void* d_ws, size_t ws_size,
                              hipStream_t stream) {
    const float* x    = (const float*)d_in[0];
    const float* Wih1 = (const float*)d_in[1];
    const float* Whh1 = (const float*)d_in[2];
    const float* bih1 = (const float*)d_in[3];
    const float* bhh1 = (const float*)d_in[4];
    const float* Wih2 = (const float*)d_in[5];
    const float* Whh2 = (const float*)d_in[6];
    const float* bih2 = (const float*)d_in[7];
    const float* bhh2 = (const float*)d_in[8];
    const float* Wlin = (const float*)d_in[9];
    const float* blin = (const float*)d_in[10];
    float* out = (float*)d_out;

    lstm2_b8_kernel<<<1, 256, 0, stream>>>(
        x, Wih1, Whh1, bih1, bhh1, Wih2, Whh2, bih2, bhh2, Wlin, blin, out);
}